// Round 4
// baseline (395.602 us; speedup 1.0000x reference)
//
#include <hip/hip_runtime.h>
#include <math.h>

#define NN 1024   // nodes
#define DD 128    // dim
#define BB 1024   // graphs

typedef float floatx4 __attribute__((ext_vector_type(4)));

__device__ __forceinline__ float waveReduceSum(float v) {
#pragma unroll
  for (int off = 32; off > 0; off >>= 1) v += __shfl_xor(v, off);
  return v;
}
__device__ __forceinline__ float waveReduceMax(float v) {
#pragma unroll
  for (int off = 32; off > 0; off >>= 1) v = fmaxf(v, __shfl_xor(v, off));
  return v;
}

// K1 prep: blocks 0..NN-1 normalize node rows, NN..NN+BB-1 normalize graph
// rows, NN+BB..NN+2*BB-1 compute gm row max/denominator. 64 threads/block.
__global__ __launch_bounds__(64) void prep_kernel(
    const float* __restrict__ ne, const float* __restrict__ ge,
    const float* __restrict__ gm, float* __restrict__ ne_n,
    float* __restrict__ ge_n, float* __restrict__ gm_max,
    float* __restrict__ gm_den) {
  int b = blockIdx.x;
  int lane = threadIdx.x;
  if (b < NN + BB) {
    const float* src;
    float* dst;
    if (b < NN) { src = ne + (size_t)b * DD; dst = ne_n + (size_t)b * DD; }
    else { src = ge + (size_t)(b - NN) * DD; dst = ge_n + (size_t)(b - NN) * DD; }
    float2 v = ((const float2*)src)[lane];
    float ss = v.x * v.x + v.y * v.y;
    ss = waveReduceSum(ss);
    float scale = 1.0f / fmaxf(sqrtf(ss), 1e-12f);
    float2 o;
    o.x = v.x * scale;
    o.y = v.y * scale;
    ((float2*)dst)[lane] = o;
  } else {
    int row = b - (NN + BB);
    const float4* r = (const float4*)(gm + (size_t)row * BB);
    float vals[16];
    float m = -INFINITY;
#pragma unroll
    for (int k = 0; k < 4; ++k) {
      float4 v = r[lane + 64 * k];
      vals[k * 4 + 0] = v.x; vals[k * 4 + 1] = v.y;
      vals[k * 4 + 2] = v.z; vals[k * 4 + 3] = v.w;
      m = fmaxf(m, fmaxf(fmaxf(v.x, v.y), fmaxf(v.z, v.w)));
    }
    m = waveReduceMax(m);
    float s = 0.f;
#pragma unroll
    for (int t = 0; t < 16; ++t) s += expf(vals[t] - m);
    s = waveReduceSum(s);
    if (lane == 0) { gm_max[row] = m; gm_den[row] = s; }
  }
}

// K2 loss: blocks 0..1023 node-loss rows; 1024..2047 graph-loss rows
// (+ graph_logits store). 16-lane group per j-row dot product.
__global__ __launch_bounds__(256) void loss_kernel(
    const float* __restrict__ nen, const float* __restrict__ gen,
    const float* __restrict__ gm, const float* __restrict__ gm_max,
    const float* __restrict__ gm_den, float* __restrict__ out_logits,
    float* __restrict__ node_partial, float* __restrict__ graph_partial) {
  int bid = blockIdx.x;
  int tid = threadIdx.x;
  int lane = tid & 63, wid = tid >> 6;
  int g = lane >> 4, gl = lane & 15;
  __shared__ float q[DD];
  __shared__ float logits[NN];
  __shared__ float red[8];

  if (bid < 1024) {
    int i = bid;
    if (tid < DD) q[tid] = nen[(size_t)i * DD + tid];
    __syncthreads();
    const float4* qv = (const float4*)q;
    float4 b0 = qv[gl * 2], b1 = qv[gl * 2 + 1];
#pragma unroll 4
    for (int p = 0; p < 64; ++p) {
      int j = p * 16 + wid * 4 + g;
      const float4* rowp = (const float4*)(nen + (size_t)j * DD);
      float4 a0 = rowp[gl * 2], a1 = rowp[gl * 2 + 1];
      float acc = a0.x * b0.x + a0.y * b0.y + a0.z * b0.z + a0.w * b0.w +
                  a1.x * b1.x + a1.y * b1.y + a1.z * b1.z + a1.w * b1.w;
      acc += __shfl_xor(acc, 1);
      acc += __shfl_xor(acc, 2);
      acc += __shfl_xor(acc, 4);
      acc += __shfl_xor(acc, 8);
      if (gl == 0) logits[j] = acc;
    }
    __syncthreads();
    float lv[4];
    float m = -INFINITY;
#pragma unroll
    for (int k = 0; k < 4; ++k) {
      lv[k] = logits[tid + 256 * k];
      m = fmaxf(m, lv[k]);
    }
    m = waveReduceMax(m);
    if (lane == 0) red[wid] = m;
    __syncthreads();
    float M = fmaxf(fmaxf(red[0], red[1]), fmaxf(red[2], red[3]));
    float s = 0.f;
#pragma unroll
    for (int k = 0; k < 4; ++k) s += expf(lv[k] - M);
    s = waveReduceSum(s);
    if (lane == 0) red[4 + wid] = s;
    __syncthreads();
    float S = red[4] + red[5] + red[6] + red[7];
    if (tid == 0) node_partial[i] = logits[i] - (M + logf(S));
  } else {
    // graph loss row i. logits matrix symmetric (bitwise: same reduction
    // order) so lpT == lp; fold both loss terms into one weighted sum.
    int i = bid - 1024;
    if (tid < DD) q[tid] = gen[(size_t)i * DD + tid];
    __syncthreads();
    const float4* qv = (const float4*)q;
    float4 b0 = qv[gl * 2], b1 = qv[gl * 2 + 1];
#pragma unroll 4
    for (int p = 0; p < 64; ++p) {
      int j = p * 16 + wid * 4 + g;
      const float4* rowp = (const float4*)(gen + (size_t)j * DD);
      float4 a0 = rowp[gl * 2], a1 = rowp[gl * 2 + 1];
      float acc = a0.x * b0.x + a0.y * b0.y + a0.z * b0.z + a0.w * b0.w +
                  a1.x * b1.x + a1.y * b1.y + a1.z * b1.z + a1.w * b1.w;
      acc += __shfl_xor(acc, 1);
      acc += __shfl_xor(acc, 2);
      acc += __shfl_xor(acc, 4);
      acc += __shfl_xor(acc, 8);
      if (gl == 0) logits[j] = acc;
    }
    __syncthreads();
    float lv[4];
    float m = -INFINITY;
#pragma unroll
    for (int k = 0; k < 4; ++k) {
      lv[k] = logits[tid + 256 * k];
      m = fmaxf(m, lv[k]);
      out_logits[(size_t)i * BB + tid + 256 * k] = lv[k];
    }
    m = waveReduceMax(m);
    if (lane == 0) red[wid] = m;
    __syncthreads();
    float M = fmaxf(fmaxf(red[0], red[1]), fmaxf(red[2], red[3]));
    float s = 0.f;
#pragma unroll
    for (int k = 0; k < 4; ++k) s += expf(lv[k] - M);
    s = waveReduceSum(s);
    if (lane == 0) red[4 + wid] = s;
    __syncthreads();
    float S = red[4] + red[5] + red[6] + red[7];
    float lse = M + logf(S);
    float gmx_i = gm_max[i];
    float inv_i = 1.0f / gm_den[i];
    float c = 0.f;
#pragma unroll
    for (int k = 0; k < 4; ++k) {
      int j = tid + 256 * k;
      float lp = lv[k] - lse;
      float wij = expf(gm[(size_t)i * BB + j] - gmx_i) * inv_i;
      float wji = expf(gm[(size_t)j * BB + i] - gm_max[j]) / gm_den[j];
      c += (wij + wji) * lp;
    }
    c = waveReduceSum(c);
    __syncthreads();
    if (lane == 0) red[wid] = c;
    __syncthreads();
    if (tid == 0) graph_partial[i] = red[0] + red[1] + red[2] + red[3];
  }
}

// K3 pairwise stream: persistent grid-stride, aligned float4 stores.
// Region element e (float index into out_pair, e in [0, 2^28)):
//   r = e>>8, c = e&255; value = c<128 ? nen[(r>>10)*128+c] : nen[(r&1023)*128+c-128]
// out_pair absolute float offset = 1048579 (== 3 mod 4), so float4-aligned
// coverage is e = 1+4k .. 4+4k for k in [0, NF4); head e=0 and tail 3
// elements are handled scalar by global thread 0.
#define NF4 67108863UL
__global__ __launch_bounds__(256) void pairwise_kernel(
    const float* __restrict__ nen, float* __restrict__ outp) {
  size_t gid = (size_t)blockIdx.x * 256 + threadIdx.x;
  size_t T = (size_t)gridDim.x * 256;
  for (size_t k = gid; k < NF4; k += T) {
    size_t e0 = 1 + 4 * k;
    floatx4 v;
#pragma unroll
    for (int kk = 0; kk < 4; ++kk) {
      size_t e = e0 + kk;
      int r = (int)(e >> 8);
      int c = (int)(e & 255);
      int row = (c < 128) ? (r >> 10) : (r & 1023);
      int col = c & 127;
      v[kk] = nen[(size_t)row * DD + col];
    }
    __builtin_nontemporal_store(v, (floatx4*)(outp + e0));
  }
  if (gid == 0) {
    // head: e = 0 -> row 0, col 0
    __builtin_nontemporal_store(nen[0], outp);
    // tail: e = 2^28 - 3 .. 2^28 - 1 -> r = 1048575 (j = 1023), c = 253..255
#pragma unroll
    for (int t = 0; t < 3; ++t) {
      size_t e = 268435453UL + t;
      __builtin_nontemporal_store(nen[(size_t)1023 * DD + 125 + t], outp + e);
    }
  }
}

// K4: deterministic final reduce of the 1024-element partial arrays.
__global__ __launch_bounds__(256) void final_kernel(
    const float* __restrict__ node_partial,
    const float* __restrict__ graph_partial, float* __restrict__ out) {
  int tid = threadIdx.x;
  int lane = tid & 63, wid = tid >> 6;
  __shared__ float red[8];
  float ns = 0.f, gs = 0.f;
#pragma unroll
  for (int k = 0; k < 4; ++k) {
    ns += node_partial[tid + 256 * k];
    gs += graph_partial[tid + 256 * k];
  }
  ns = waveReduceSum(ns);
  gs = waveReduceSum(gs);
  if (lane == 0) { red[wid] = ns; red[4 + wid] = gs; }
  __syncthreads();
  if (tid == 0) {
    float nsum = red[0] + red[1] + red[2] + red[3];
    float gsum = red[4] + red[5] + red[6] + red[7];
    float node_loss = -nsum / (float)NN;
    float graph_loss = -gsum / (float)BB;
    float loss = 0.5f * node_loss + 0.5f * graph_loss;
    out[0] = loss;
    out[1] = node_loss;
    out[2] = graph_loss;
  }
}

extern "C" void kernel_launch(void* const* d_in, const int* in_sizes, int n_in,
                              void* d_out, int out_size, void* d_ws,
                              size_t ws_size, hipStream_t stream) {
  const float* ne = (const float*)d_in[0];   // [1024,128]
  const float* ge = (const float*)d_in[1];   // [1024,128]
  const float* gm = (const float*)d_in[2];   // [1024,1024]
  float* out = (float*)d_out;
  float* ws = (float*)d_ws;

  float* ne_n = ws;                    // 131072
  float* ge_n = ws + 131072;           // 131072
  float* gm_max = ws + 262144;         // 1024
  float* gm_den = ws + 263168;         // 1024
  float* node_partial = ws + 264192;   // 1024
  float* graph_partial = ws + 265216;  // 1024

  float* out_logits = out + 3;                       // [1024,1024]
  float* out_pair = out + 3 + (size_t)NN * NN;       // [1024*1024, 256]

  hipLaunchKernelGGL(prep_kernel, dim3(NN + 2 * BB), dim3(64), 0, stream,
                     ne, ge, gm, ne_n, ge_n, gm_max, gm_den);
  hipLaunchKernelGGL(loss_kernel, dim3(2048), dim3(256), 0, stream,
                     ne_n, ge_n, gm, gm_max, gm_den, out_logits,
                     node_partial, graph_partial);
  hipLaunchKernelGGL(pairwise_kernel, dim3(2048), dim3(256), 0, stream,
                     ne_n, out_pair);
  hipLaunchKernelGGL(final_kernel, dim3(1), dim3(256), 0, stream,
                     node_partial, graph_partial, out);
}

// Round 5
// 309.277 us; speedup vs baseline: 1.2791x; 1.2791x over previous
//
#include <hip/hip_runtime.h>
#include <math.h>

#define NN 1024   // nodes
#define DD 128    // dim
#define BB 1024   // graphs

typedef float floatx4 __attribute__((ext_vector_type(4)));

__device__ __forceinline__ float waveReduceSum(float v) {
#pragma unroll
  for (int off = 32; off > 0; off >>= 1) v += __shfl_xor(v, off);
  return v;
}
__device__ __forceinline__ float waveReduceMax(float v) {
#pragma unroll
  for (int off = 32; off > 0; off >>= 1) v = fmaxf(v, __shfl_xor(v, off));
  return v;
}

// K1 prep: blocks 0..NN-1 normalize node rows, NN..NN+BB-1 normalize graph
// rows, NN+BB..NN+2*BB-1 compute gm row max/denominator. 64 threads/block.
__global__ __launch_bounds__(64) void prep_kernel(
    const float* __restrict__ ne, const float* __restrict__ ge,
    const float* __restrict__ gm, float* __restrict__ ne_n,
    float* __restrict__ ge_n, float* __restrict__ gm_max,
    float* __restrict__ gm_den) {
  int b = blockIdx.x;
  int lane = threadIdx.x;
  if (b < NN + BB) {
    const float* src;
    float* dst;
    if (b < NN) { src = ne + (size_t)b * DD; dst = ne_n + (size_t)b * DD; }
    else { src = ge + (size_t)(b - NN) * DD; dst = ge_n + (size_t)(b - NN) * DD; }
    float2 v = ((const float2*)src)[lane];
    float ss = v.x * v.x + v.y * v.y;
    ss = waveReduceSum(ss);
    float scale = 1.0f / fmaxf(sqrtf(ss), 1e-12f);
    float2 o;
    o.x = v.x * scale;
    o.y = v.y * scale;
    ((float2*)dst)[lane] = o;
  } else {
    int row = b - (NN + BB);
    const float4* r = (const float4*)(gm + (size_t)row * BB);
    float vals[16];
    float m = -INFINITY;
#pragma unroll
    for (int k = 0; k < 4; ++k) {
      float4 v = r[lane + 64 * k];
      vals[k * 4 + 0] = v.x; vals[k * 4 + 1] = v.y;
      vals[k * 4 + 2] = v.z; vals[k * 4 + 3] = v.w;
      m = fmaxf(m, fmaxf(fmaxf(v.x, v.y), fmaxf(v.z, v.w)));
    }
    m = waveReduceMax(m);
    float s = 0.f;
#pragma unroll
    for (int t = 0; t < 16; ++t) s += expf(vals[t] - m);
    s = waveReduceSum(s);
    if (lane == 0) { gm_max[row] = m; gm_den[row] = s; }
  }
}

// K2 loss: blocks 0..1023 node-loss rows; 1024..2047 graph-loss rows
// (+ graph_logits store). 16-lane group per j-row dot product.
__global__ __launch_bounds__(256) void loss_kernel(
    const float* __restrict__ nen, const float* __restrict__ gen,
    const float* __restrict__ gm, const float* __restrict__ gm_max,
    const float* __restrict__ gm_den, float* __restrict__ out_logits,
    float* __restrict__ node_partial, float* __restrict__ graph_partial) {
  int bid = blockIdx.x;
  int tid = threadIdx.x;
  int lane = tid & 63, wid = tid >> 6;
  int g = lane >> 4, gl = lane & 15;
  __shared__ float q[DD];
  __shared__ float logits[NN];
  __shared__ float red[8];

  if (bid < 1024) {
    int i = bid;
    if (tid < DD) q[tid] = nen[(size_t)i * DD + tid];
    __syncthreads();
    const float4* qv = (const float4*)q;
    float4 b0 = qv[gl * 2], b1 = qv[gl * 2 + 1];
#pragma unroll 4
    for (int p = 0; p < 64; ++p) {
      int j = p * 16 + wid * 4 + g;
      const float4* rowp = (const float4*)(nen + (size_t)j * DD);
      float4 a0 = rowp[gl * 2], a1 = rowp[gl * 2 + 1];
      float acc = a0.x * b0.x + a0.y * b0.y + a0.z * b0.z + a0.w * b0.w +
                  a1.x * b1.x + a1.y * b1.y + a1.z * b1.z + a1.w * b1.w;
      acc += __shfl_xor(acc, 1);
      acc += __shfl_xor(acc, 2);
      acc += __shfl_xor(acc, 4);
      acc += __shfl_xor(acc, 8);
      if (gl == 0) logits[j] = acc;
    }
    __syncthreads();
    float lv[4];
    float m = -INFINITY;
#pragma unroll
    for (int k = 0; k < 4; ++k) {
      lv[k] = logits[tid + 256 * k];
      m = fmaxf(m, lv[k]);
    }
    m = waveReduceMax(m);
    if (lane == 0) red[wid] = m;
    __syncthreads();
    float M = fmaxf(fmaxf(red[0], red[1]), fmaxf(red[2], red[3]));
    float s = 0.f;
#pragma unroll
    for (int k = 0; k < 4; ++k) s += expf(lv[k] - M);
    s = waveReduceSum(s);
    if (lane == 0) red[4 + wid] = s;
    __syncthreads();
    float S = red[4] + red[5] + red[6] + red[7];
    if (tid == 0) node_partial[i] = logits[i] - (M + logf(S));
  } else {
    // graph loss row i. logits matrix symmetric (bitwise: same reduction
    // order) so lpT == lp; fold both loss terms into one weighted sum.
    int i = bid - 1024;
    if (tid < DD) q[tid] = gen[(size_t)i * DD + tid];
    __syncthreads();
    const float4* qv = (const float4*)q;
    float4 b0 = qv[gl * 2], b1 = qv[gl * 2 + 1];
#pragma unroll 4
    for (int p = 0; p < 64; ++p) {
      int j = p * 16 + wid * 4 + g;
      const float4* rowp = (const float4*)(gen + (size_t)j * DD);
      float4 a0 = rowp[gl * 2], a1 = rowp[gl * 2 + 1];
      float acc = a0.x * b0.x + a0.y * b0.y + a0.z * b0.z + a0.w * b0.w +
                  a1.x * b1.x + a1.y * b1.y + a1.z * b1.z + a1.w * b1.w;
      acc += __shfl_xor(acc, 1);
      acc += __shfl_xor(acc, 2);
      acc += __shfl_xor(acc, 4);
      acc += __shfl_xor(acc, 8);
      if (gl == 0) logits[j] = acc;
    }
    __syncthreads();
    float lv[4];
    float m = -INFINITY;
#pragma unroll
    for (int k = 0; k < 4; ++k) {
      lv[k] = logits[tid + 256 * k];
      m = fmaxf(m, lv[k]);
      out_logits[(size_t)i * BB + tid + 256 * k] = lv[k];
    }
    m = waveReduceMax(m);
    if (lane == 0) red[wid] = m;
    __syncthreads();
    float M = fmaxf(fmaxf(red[0], red[1]), fmaxf(red[2], red[3]));
    float s = 0.f;
#pragma unroll
    for (int k = 0; k < 4; ++k) s += expf(lv[k] - M);
    s = waveReduceSum(s);
    if (lane == 0) red[4 + wid] = s;
    __syncthreads();
    float S = red[4] + red[5] + red[6] + red[7];
    float lse = M + logf(S);
    float gmx_i = gm_max[i];
    float inv_i = 1.0f / gm_den[i];
    float c = 0.f;
#pragma unroll
    for (int k = 0; k < 4; ++k) {
      int j = tid + 256 * k;
      float lp = lv[k] - lse;
      float wij = expf(gm[(size_t)i * BB + j] - gmx_i) * inv_i;
      float wji = expf(gm[(size_t)j * BB + i] - gm_max[j]) / gm_den[j];
      c += (wij + wji) * lp;
    }
    c = waveReduceSum(c);
    __syncthreads();
    if (lane == 0) red[wid] = c;
    __syncthreads();
    if (tid == 0) graph_partial[i] = red[0] + red[1] + red[2] + red[3];
  }
}

// K3 pairwise stream: one ALIGNED float4 cached store per thread.
// Region element e (float index into out_pair, e in [0, 2^28)):
//   r = e>>8, c = e&255; val = c<128 ? nen[(r>>10)*128+c] : nen[(r&1023)*128+c-128]
// out_pair absolute float offset = 1048579 == 3 (mod 4), so e = 1+4k is a
// 16B-aligned slot. Thread k stores floats [1+4k .. 4+4k]. Head e=0 and the
// 3-float tail are done by thread 0. No nontemporal: let L2 merge line seams.
#define NF4 67108863UL
__global__ __launch_bounds__(256) void pairwise_kernel(
    const float* __restrict__ nen, float* __restrict__ outp) {
  size_t k = (size_t)blockIdx.x * 256 + threadIdx.x;
  if (k < NF4) {
    size_t e0 = 1 + 4 * k;
    floatx4 v;
#pragma unroll
    for (int kk = 0; kk < 4; ++kk) {
      size_t e = e0 + kk;
      int r = (int)(e >> 8);
      int c = (int)(e & 255);
      int row = (c < 128) ? (r >> 10) : (r & 1023);
      int col = c & 127;
      v[kk] = nen[(size_t)row * DD + col];
    }
    *(floatx4*)(outp + e0) = v;  // aligned 16B cached store
  }
  if (k == 0) {
    outp[0] = nen[0];  // head: e=0 -> row 0, col 0
    // tail: e = 2^28-3 .. 2^28-1 -> r = 1048575 (j=1023), c = 253..255
    outp[268435453UL] = nen[1023 * DD + 125];
    outp[268435454UL] = nen[1023 * DD + 126];
    outp[268435455UL] = nen[1023 * DD + 127];
  }
}

// K4: deterministic final reduce of the 1024-element partial arrays.
__global__ __launch_bounds__(256) void final_kernel(
    const float* __restrict__ node_partial,
    const float* __restrict__ graph_partial, float* __restrict__ out) {
  int tid = threadIdx.x;
  int lane = tid & 63, wid = tid >> 6;
  __shared__ float red[8];
  float ns = 0.f, gs = 0.f;
#pragma unroll
  for (int k = 0; k < 4; ++k) {
    ns += node_partial[tid + 256 * k];
    gs += graph_partial[tid + 256 * k];
  }
  ns = waveReduceSum(ns);
  gs = waveReduceSum(gs);
  if (lane == 0) { red[wid] = ns; red[4 + wid] = gs; }
  __syncthreads();
  if (tid == 0) {
    float nsum = red[0] + red[1] + red[2] + red[3];
    float gsum = red[4] + red[5] + red[6] + red[7];
    float node_loss = -nsum / (float)NN;
    float graph_loss = -gsum / (float)BB;
    float loss = 0.5f * node_loss + 0.5f * graph_loss;
    out[0] = loss;
    out[1] = node_loss;
    out[2] = graph_loss;
  }
}

extern "C" void kernel_launch(void* const* d_in, const int* in_sizes, int n_in,
                              void* d_out, int out_size, void* d_ws,
                              size_t ws_size, hipStream_t stream) {
  const float* ne = (const float*)d_in[0];   // [1024,128]
  const float* ge = (const float*)d_in[1];   // [1024,128]
  const float* gm = (const float*)d_in[2];   // [1024,1024]
  float* out = (float*)d_out;
  float* ws = (float*)d_ws;

  float* ne_n = ws;                    // 131072
  float* ge_n = ws + 131072;           // 131072
  float* gm_max = ws + 262144;         // 1024
  float* gm_den = ws + 263168;         // 1024
  float* node_partial = ws + 264192;   // 1024
  float* graph_partial = ws + 265216;  // 1024

  float* out_logits = out + 3;                       // [1024,1024]
  float* out_pair = out + 3 + (size_t)NN * NN;       // [1024*1024, 256]

  hipLaunchKernelGGL(prep_kernel, dim3(NN + 2 * BB), dim3(64), 0, stream,
                     ne, ge, gm, ne_n, ge_n, gm_max, gm_den);
  hipLaunchKernelGGL(loss_kernel, dim3(2048), dim3(256), 0, stream,
                     ne_n, ge_n, gm, gm_max, gm_den, out_logits,
                     node_partial, graph_partial);
  hipLaunchKernelGGL(pairwise_kernel, dim3(262144), dim3(256), 0, stream,
                     ne_n, out_pair);
  hipLaunchKernelGGL(final_kernel, dim3(1), dim3(256), 0, stream,
                     node_partial, graph_partial, out);
}